// Round 1
// 289.667 us; speedup vs baseline: 1.1684x; 1.1684x over previous
//
#include <hip/hip_runtime.h>
#include <math.h>

#define A_TOT   10647
#define BATCH   64
#define NTGT    50
#define NC      80
#define MAXHIT  512
#define TOT_CELLS (BATCH * A_TOT)          // 681408
#define NBD     666                        // ceil(681408/1024) dense blocks
#define GRID    (BATCH + NBD)              // 730 (sparse blocks first)

struct Rec {
    int cell;
    float tx, ty, tw, th, wwh, tconf;
    unsigned c0, c1, c2;     // 80-bit class set
};

// ---------------------------------------------------------------------------
// K1: one kernel, two block roles.
//   bid <  BATCH : "sparse" block — full target matching for batch b in LDS,
//                  then xywh MSE, masked conf BCE, hit-cell cancellation,
//                  class BCE.
//   bid >= BATCH : "dense" block — sums -log(1-conf) over 1024 cells.
// Merge of duplicate best-cells is PARALLEL (one lane per target):
//   scalar fields: last-write-wins == max-target-index-wins per cell;
//   class bits:    OR over all targets in the cell (order-independent).
// This replaces the old thread-0 serial merge (~1000 dependent ds_read
// iterations ≈ 120k cycles on one lane — the block critical path).
// ---------------------------------------------------------------------------
__global__ __launch_bounds__(256) void sumK(const float* __restrict__ pred,
                                            const float* __restrict__ tgt,
                                            double* __restrict__ part,
                                            int* __restrict__ counts) {
    const int bid = blockIdx.x;
    const int tid = threadIdx.x;
    double s1 = 0.0, sA = 0.0, sC = 0.0;

    if (bid >= BATCH) {
        // ---------------- dense role ----------------
        const int base = (bid - BATCH) * 1024 + tid;
        const int i0 = base, i1 = base + 256, i2 = base + 512, i3 = base + 768;
        float v0 = (i0 < TOT_CELLS) ? pred[(size_t)i0 * 85 + 4] : 0.0f;
        float v1 = (i1 < TOT_CELLS) ? pred[(size_t)i1 * 85 + 4] : 0.0f;
        float v2 = (i2 < TOT_CELLS) ? pred[(size_t)i2 * 85 + 4] : 0.0f;
        float v3 = (i3 < TOT_CELLS) ? pred[(size_t)i3 * 85 + 4] : 0.0f;
        s1 = -((double)logf(1.0f - v0) + (double)logf(1.0f - v1) +
               (double)logf(1.0f - v2) + (double)logf(1.0f - v3));
    } else {
        // ---------------- sparse role: batch b ----------------
        const int b = bid;
        __shared__ int   s_valid[NTGT];
        __shared__ int   s_idx[NTGT];
        __shared__ float s_tx[NTGT], s_ty[NTGT], s_tw[NTGT], s_th[NTGT];
        __shared__ float s_wwh[NTGT], s_tc[NTGT];
        __shared__ int   s_cls[NTGT];
        __shared__ Rec   s_rec[NTGT];
        __shared__ int   s_cnt;
        __shared__ unsigned s_bm[336];      // 10647-bit hit bitmap
        __shared__ int   s_hits[MAXHIT];
        __shared__ int   s_hc;

        for (int i = tid; i < 336; i += 256) s_bm[i] = 0u;
        if (tid == 0) { s_hc = 0; s_cnt = 0; }
        __syncthreads();

        const float fs[3] = {13.f, 26.f, 52.f};
        const int   ln[3] = {0, 507, 2535};
        const float aw[3][3] = {{3.625f, 4.875f, 11.65625f},
                                {1.875f, 3.875f, 3.6875f},
                                {1.25f,  2.0f,   4.125f}};
        const float ah[3][3] = {{2.8125f, 6.1875f, 10.1875f},
                                {3.8125f, 2.8125f, 7.4375f},
                                {1.625f,  3.75f,   2.875f}};

        if (tid < NTGT) {
            const float* t = tgt + (size_t)(b * NTGT + tid) * 5;
            float t0 = t[0], t1 = t[1], t2 = t[2], t3 = t[3], t4 = t[4];
            int valid = ((t0 + t1 + t2 + t3 + t4) != 0.0f);
            s_valid[tid] = valid;
            if (valid) {
                float best_m_iou = -1.f;
                int bf = 0, best_a = 0, gi_b = 0, gj_b = 0;
                for (int m = 0; m < 3; m++) {
                    float gw = t3 * fs[m], gh = t4 * fs[m];
                    int gi = (int)floorf(t1 * fs[m]);
                    int gj = (int)floorf(t2 * fs[m]);
                    float bi = -1.f; int bk = 0;
                    for (int k = 0; k < 3; k++) {
                        float in_ = fminf(gw, aw[m][k]) * fminf(gh, ah[m][k]);
                        float un  = gw * gh + aw[m][k] * ah[m][k] - in_;
                        float iou = in_ / (un + 1e-16f);
                        if (iou > bi) { bi = iou; bk = k; }
                        if (iou > 0.5f) {                     // IGNORE_THR hit
                            int cell = ln[m] + 3 * gi * gj + k;
                            unsigned bit = 1u << (cell & 31);
                            unsigned old = atomicOr(&s_bm[cell >> 5], bit);
                            if (!(old & bit)) {
                                int pos = atomicAdd(&s_hc, 1);
                                s_hits[pos] = cell;
                            }
                        }
                    }
                    if (bi > best_m_iou) {
                        best_m_iou = bi; bf = m; best_a = bk; gi_b = gi; gj_b = gj;
                    }
                }
                s_idx[tid] = ln[bf] + 3 * gi_b * gj_b + best_a;
                s_tx[tid]  = t1 * 416.f;
                s_ty[tid]  = t2 * 416.f;
                s_tw[tid]  = t3 * 416.f;
                s_th[tid]  = t4 * 416.f;
                s_wwh[tid] = 2.0f - t3 * t4;
                s_tc[tid]  = best_m_iou;
                s_cls[tid] = (int)t0;
            }
        }
        __syncthreads();

        // ---- parallel merge: one lane per target ----
        // All LDS reads in the j-loop are same-address across lanes
        // (broadcast, conflict-free) and independent (pipelined).
        if (tid < NTGT && s_valid[tid]) {
            const int cell = s_idx[tid];
            bool winner = true;
            unsigned c0 = 0, c1 = 0, c2 = 0;
            for (int j = 0; j < NTGT; j++) {
                if (!s_valid[j] || s_idx[j] != cell) continue;
                if (j > tid) winner = false;      // a later target owns the cell
                int c = s_cls[j];
                if (c < 32)       c0 |= 1u << c;
                else if (c < 64)  c1 |= 1u << (c - 32);
                else              c2 |= 1u << (c - 64);
            }
            if (winner) {
                int pos = atomicAdd(&s_cnt, 1);   // compaction order irrelevant
                Rec r;
                r.cell = cell;
                r.tx = s_tx[tid];  r.ty = s_ty[tid];
                r.tw = s_tw[tid];  r.th = s_th[tid];
                r.wwh = s_wwh[tid]; r.tconf = s_tc[tid];
                r.c0 = c0; r.c1 = c1; r.c2 = c2;
                s_rec[pos] = r;
            }
        }
        __syncthreads();
        const int cnt = s_cnt;
        const int hc  = s_hc;
        if (tid == 0) counts[b] = cnt;

        // cancel hit cells (they have noobj == 0 in the reference)
        for (int i = tid; i < hc; i += 256) {
            int cell = s_hits[i];
            float conf = pred[((size_t)b * A_TOT + cell) * 85 + 4];
            s1 += (double)logf(1.0f - conf);
        }
        // masked-cell terms: xywh MSE + conf BCE
        for (int r = tid; r < cnt; r += 256) {
            Rec rec = s_rec[r];
            const float* p = pred + ((size_t)b * A_TOT + rec.cell) * 85;
            float x = p[0], y = p[1], w = p[2], h = p[3], conf = p[4];
            float wwh = rec.wwh;
            float dx = x * wwh - rec.tx * wwh;
            float dy = y * wwh - rec.ty * wwh;
            float dw = w * wwh - rec.tw * wwh;
            float dh = h * wwh - rec.th * wwh;
            sA += (double)(dx * dx) + (double)(dy * dy) +
                  (double)(dw * dw) + (double)(dh * dh);
            float t = rec.tconf;
            sA -= (double)(t * logf(conf) + (1.0f - t) * logf(1.0f - conf));
        }
        // class BCE over cnt*80 elements
        for (int q = tid; q < cnt * NC; q += 256) {
            int r = q / NC, c = q - r * NC;
            Rec rec = s_rec[r];
            float pc = pred[((size_t)b * A_TOT + rec.cell) * 85 + 5 + c];
            unsigned bit;
            if (c < 32)       bit = (rec.c0 >> c) & 1u;
            else if (c < 64)  bit = (rec.c1 >> (c - 32)) & 1u;
            else              bit = (rec.c2 >> (c - 64)) & 1u;
            sC -= bit ? (double)logf(pc) : (double)logf(1.0f - pc);
        }
    }

    // block reduction (wave64 shuffle + LDS across 4 waves), then one
    // unconditional slot write per block — no atomics, no init required.
    for (int off = 32; off; off >>= 1) {
        s1 += __shfl_down(s1, off, 64);
        sA += __shfl_down(sA, off, 64);
        sC += __shfl_down(sC, off, 64);
    }
    __shared__ double w1[4], wA[4], wC[4];
    int lane = tid & 63, w = tid >> 6;
    if (lane == 0) { w1[w] = s1; wA[w] = sA; wC[w] = sC; }
    __syncthreads();
    if (tid == 0) {
        part[bid * 3 + 0] = w1[0] + w1[1] + w1[2] + w1[3];
        part[bid * 3 + 1] = wA[0] + wA[1] + wA[2] + wA[3];
        part[bid * 3 + 2] = wC[0] + wC[1] + wC[2] + wC[3];
    }
}

// ---------------------------------------------------------------------------
// K2: reduce the 730 partial slots + 64 counts, combine.
// ---------------------------------------------------------------------------
__global__ __launch_bounds__(256) void finalK(const double* __restrict__ part,
                                              const int* __restrict__ counts,
                                              float* __restrict__ out) {
    const int tid = threadIdx.x;
    double s1 = 0.0, sA = 0.0, sC = 0.0;
    for (int i = tid; i < GRID; i += 256) {
        s1 += part[i * 3 + 0];
        sA += part[i * 3 + 1];
        sC += part[i * 3 + 2];
    }
    int np = (tid < BATCH) ? counts[tid] : 0;
    for (int off = 32; off; off >>= 1) {
        s1 += __shfl_down(s1, off, 64);
        sA += __shfl_down(sA, off, 64);
        sC += __shfl_down(sC, off, 64);
        np += __shfl_down(np, off, 64);
    }
    __shared__ double w1[4], wA[4], wC[4];
    __shared__ int    wN[4];
    int lane = tid & 63, w = tid >> 6;
    if (lane == 0) { w1[w] = s1; wA[w] = sA; wC[w] = sC; wN[w] = np; }
    __syncthreads();
    if (tid == 0) {
        double f1 = w1[0] + w1[1] + w1[2] + w1[3];
        double fA = wA[0] + wA[1] + wA[2] + wA[3];
        double fC = wC[0] + wC[1] + wC[2] + wC[3];
        int npos  = wN[0] + wN[1] + wN[2] + wN[3];
        double total = (fA + 0.5 * f1) / (double)TOT_CELLS;
        if (npos > 0) total += fC / ((double)npos * (double)NC);
        out[0] = (float)total;
    }
}

extern "C" void kernel_launch(void* const* d_in, const int* in_sizes, int n_in,
                              void* d_out, int out_size, void* d_ws, size_t ws_size,
                              hipStream_t stream) {
    const float* pred = (const float*)d_in[0];   // (64, 10647, 85) f32
    const float* tgt  = (const float*)d_in[1];   // (64, 50, 5) f32
    // d_in[2] = stride (always 32; fsizes/last_num hardcoded)

    char* ws = (char*)d_ws;
    double* part   = (double*)ws;                 // GRID*3 doubles = 17.5 KB
    int*    counts = (int*)(ws + 32768);          // 64 ints

    sumK<<<GRID, 256, 0, stream>>>(pred, tgt, part, counts);
    finalK<<<1, 256, 0, stream>>>(part, counts, (float*)d_out);
}